// Round 8
// baseline (734.271 us; speedup 1.0000x reference)
//
#include <hip/hip_runtime.h>
#include <hip/hip_fp16.h>

#define NN 50000   // nodes
#define NE 100000  // edges
#define NB 512     // graphs
// H = 64, F_NODE = 16, F_EDGE = 8, T = 3

typedef _Float16 f16x8 __attribute__((ext_vector_type(8)));
typedef _Float16 f16x4 __attribute__((ext_vector_type(4)));
typedef float f32x4  __attribute__((ext_vector_type(4)));
typedef float f32x16 __attribute__((ext_vector_type(16)));

__device__ __forceinline__ float sigm(float v) { return 1.0f / (1.0f + __expf(-v)); }
__device__ __forceinline__ float tanh_fast(float v) {
    float e = __expf(-2.0f * fabsf(v));
    float t = (1.0f - e) / (1.0f + e);
    return v < 0.f ? -t : t;
}

// Fused prologue: one dispatch does node_in, edge_l1, pack_b32 (264 kt, zero-padded),
// pack_gru, agg zero-fill, d_out zero. Segments by blockIdx.
#define S0 12500               // node_in: NN*64/256
#define S1 (S0 + 25000)        // edge_l1: NE*64/256
#define S2 (S1 + 1056)         // pack_b32: 264*1024/256
#define S3 (S2 + 96)           // pack_gru: 24576/256
#define S4 (S3 + 3125)         // agg fill: NN*16 float4 /256
#define S5 (S4 + 2)            // d_out zero: 512/256
__global__ __launch_bounds__(256) void prologue_kernel(
    const float* __restrict__ nf, const float* __restrict__ Win, const float* __restrict__ bin_,
    const float* __restrict__ ef, const float* __restrict__ We1, const float* __restrict__ be1,
    const float* __restrict__ We2, const float* __restrict__ be2,
    const float* __restrict__ Wih, const float* __restrict__ Whh,
    __half* __restrict__ xh, __half* __restrict__ ehh,
    __half* __restrict__ Bp, __half* __restrict__ WG,
    float* __restrict__ agg, float* __restrict__ outp)
{
    const int b = blockIdx.x;
    if (b < S0) {
        int idx = b * 256 + threadIdx.x;
        int n = idx >> 6, h = idx & 63;
        float acc = bin_[h];
        #pragma unroll
        for (int f = 0; f < 16; f++) acc += nf[n * 16 + f] * Win[h * 16 + f];
        xh[idx] = __float2half(acc);
    } else if (b < S1) {
        int idx = (b - S0) * 256 + threadIdx.x;
        int e = idx >> 6, k = idx & 63;
        float acc = be1[k];
        #pragma unroll
        for (int f = 0; f < 8; f++) acc += ef[e * 8 + f] * We1[k * 8 + f];
        ehh[idx] = __float2half(fmaxf(acc, 0.0f));
    } else if (b < S2) {
        int idx = (b - S1) * 256 + threadIdx.x;
        int i  = idx & 7;
        int n  = (idx >> 3) & 31;
        int hi = (idx >> 8) & 1;
        int nt = (idx >> 9) & 1;
        int kt = idx >> 10;
        int p  = kt * 16 + hi * 8 + i;
        int col = nt * 32 + n;
        float v = 0.f;
        if (p < 4096) {
            int j = p >> 6, k = p & 63;
            v = We2[((size_t)(col * 64 + j)) * 64 + k];
        } else if (p < 4160) {
            v = be2[col * 64 + (p - 4096)];
        }
        Bp[idx] = __float2half(v);
    } else if (b < S3) {
        int idx = (b - S2) * 256 + threadIdx.x;
        int kk = idx & 31;
        int n  = (idx >> 5) & 15;
        int nt = (idx >> 9) % 24;
        int kt = (idx >> 9) / 24;
        int k = kt * 32 + kk;
        int col192 = (nt % 12) * 16 + n;
        int gate = col192 >> 6, h = col192 & 63;
        const float* src = (nt < 12) ? Wih : Whh;
        WG[idx] = __float2half(src[((size_t)(gate * 64 + h)) * 64 + k]);
    } else if (b < S4) {
        int idx = (b - S3) * 256 + threadIdx.x;
        if (idx < NN * 16)
            *((float4*)agg + idx) = make_float4(0.f, 0.f, 0.f, 0.f);
    } else {
        int idx = (b - S4) * 256 + threadIdx.x;
        if (idx < NB) outp[idx] = 0.f;
    }
}

// Message GEMM v8: 2-wave blocks, 128 edges (64/wave, mt=2), 32x32x16 MFMA.
// B double-buffered in LDS (8-kt = 16 KB chunks, 33 chunks, Bp padded to 264 kt);
// one barrier per chunk; chunk c+1 global loads issued before computing chunk c.
// LDS 51 KB -> 3 blocks/CU; 782 blocks = 3.05/CU (balanced).
__global__ __launch_bounds__(128, 2) void msg_kernel(
    const __half* __restrict__ xh, const __half* __restrict__ ehh,
    const __half* __restrict__ Bp,
    const int* __restrict__ Esrc, const int* __restrict__ Etgt,
    float* __restrict__ agg)
{
    __shared__ __attribute__((aligned(16))) __half xs[128 * 72];   // 18.4 KB
    __shared__ __attribute__((aligned(16))) __half bst[2][8192];   // 2 x 16 KB
    __shared__ int tgt_s[128];
    const int tid = threadIdx.x;
    const int e0 = blockIdx.x * 128;
    const int w = tid >> 6, lane = tid & 63;
    const int n32 = lane & 31, hi = lane >> 5;

    {   // stage 128 gathered f16 source rows, one per thread
        const int e = e0 + tid;
        const bool ok = (e < NE);
        const int src = ok ? Esrc[e] : 0;
        tgt_s[tid] = ok ? Etgt[e] : -1;
        const uint4* xsrc = (const uint4*)(xh + (size_t)src * 64);
        #pragma unroll
        for (int i = 0; i < 8; i++) {
            uint4 v = ok ? xsrc[i] : make_uint4(0, 0, 0, 0);
            *(uint4*)(&xs[tid * 72 + i * 8]) = v;
        }
    }

    // per-lane eh cache: ehc[mt][c4] = eh[edge][c4*16 + hi*8 .. +8] as 4x half2
    __half2 ehc[2][4][4];
    #pragma unroll
    for (int mt = 0; mt < 2; mt++) {
        const int e = e0 + w * 64 + mt * 32 + n32;
        if (e < NE) {
            #pragma unroll
            for (int c4 = 0; c4 < 4; c4++) {
                union { uint4 u; __half2 h[4]; } u;
                u.u = *(const uint4*)(ehh + (size_t)e * 64 + c4 * 16 + hi * 8);
                #pragma unroll
                for (int q = 0; q < 4; q++) ehc[mt][c4][q] = u.h[q];
            }
        } else {
            __half2 z = __half2half2(__float2half(0.f));
            #pragma unroll
            for (int c4 = 0; c4 < 4; c4++)
                #pragma unroll
                for (int q = 0; q < 4; q++) ehc[mt][c4][q] = z;
        }
    }

    f32x16 acc[2][2];
    #pragma unroll
    for (int a = 0; a < 2; a++)
        #pragma unroll
        for (int b = 0; b < 2; b++)
            #pragma unroll
            for (int q = 0; q < 16; q++) acc[a][b][q] = 0.f;

    const int rbase = w * 64;
    const uint4* gB = (const uint4*)Bp;   // chunk c = uint4 [c*1024 .. +1024)

    uint4 breg[8];
    #pragma unroll
    for (int i = 0; i < 8; i++) breg[i] = gB[i * 128 + tid];
    #pragma unroll
    for (int i = 0; i < 8; i++) *(uint4*)(&bst[0][(i * 128 + tid) * 8]) = breg[i];
    __syncthreads();   // covers xs staging + buf0

    #pragma unroll 1
    for (int c = 0; c < 33; c++) {
        const int buf = c & 1;
        if (c + 1 < 33) {
            #pragma unroll
            for (int i = 0; i < 8; i++) breg[i] = gB[(c + 1) * 1024 + i * 128 + tid];
        }
        const __half* blane = bst[buf] + hi * 256 + n32 * 8;

        if (c < 32) {
            __half xj[2][2];   // [mt][jq], j = c*2 + jq
            #pragma unroll
            for (int mt = 0; mt < 2; mt++) {
                __half2 t = *(const __half2*)(xs + (rbase + mt * 32 + n32) * 72 + c * 2);
                xj[mt][0] = t.x; xj[mt][1] = t.y;
            }
            #pragma unroll
            for (int u = 0; u < 8; u++) {
                f16x8 b0 = *(const f16x8*)(blane + u * 1024);
                f16x8 b1 = *(const f16x8*)(blane + u * 1024 + 512);
                const int c4 = u & 3;
                const int jq = u >> 2;
                #pragma unroll
                for (int mt = 0; mt < 2; mt++) {
                    __half2 xv2 = __half2half2(xj[mt][jq]);
                    union { __half2 h[4]; f16x8 v; } a;
                    #pragma unroll
                    for (int q = 0; q < 4; q++) a.h[q] = __hmul2(xv2, ehc[mt][c4][q]);
                    acc[mt][0] = __builtin_amdgcn_mfma_f32_32x32x16_f16(a.v, b0, acc[mt][0], 0, 0, 0);
                    acc[mt][1] = __builtin_amdgcn_mfma_f32_32x32x16_f16(a.v, b1, acc[mt][1], 0, 0, 0);
                }
            }
        } else {
            // bias kts 256..259 (260..263 are zero-padded): A = x[edge][jj] from xs
            #pragma unroll
            for (int u = 0; u < 8; u++) {
                f16x8 b0 = *(const f16x8*)(blane + u * 1024);
                f16x8 b1 = *(const f16x8*)(blane + u * 1024 + 512);
                const int v = u & 3;
                #pragma unroll
                for (int mt = 0; mt < 2; mt++) {
                    f16x8 a = *(const f16x8*)(xs + (rbase + mt * 32 + n32) * 72 + v * 16 + hi * 8);
                    acc[mt][0] = __builtin_amdgcn_mfma_f32_32x32x16_f16(a, b0, acc[mt][0], 0, 0, 0);
                    acc[mt][1] = __builtin_amdgcn_mfma_f32_32x32x16_f16(a, b1, acc[mt][1], 0, 0, 0);
                }
            }
        }

        if (c + 1 < 33) {
            #pragma unroll
            for (int i = 0; i < 8; i++)
                *(uint4*)(&bst[buf ^ 1][(i * 128 + tid) * 8]) = breg[i];
        }
        __syncthreads();
    }

    // C/D 32x32 layout: col = lane&31, row = (reg&3) + 8*(reg>>2) + 4*hi
    #pragma unroll
    for (int mt = 0; mt < 2; mt++) {
        #pragma unroll
        for (int r = 0; r < 16; r++) {
            const int rowe = (r & 3) + 8 * (r >> 2) + 4 * hi;
            const int t = tgt_s[rbase + mt * 32 + rowe];
            if (t >= 0) {
                atomicAdd(agg + (size_t)t * 64 + n32, acc[mt][0][r]);
                atomicAdd(agg + (size_t)t * 64 + 32 + n32, acc[mt][1][r]);
            }
        }
    }
}

// GRU v4: f16 state. Stages agg(f32->f16) + xh into LDS, MFMA gates,
// writes xh back coalesced, zeroes agg for the next step.
__global__ __launch_bounds__(256, 2) void gru_kernel(
    float* __restrict__ agg, __half* __restrict__ xh,
    const __half* __restrict__ WG,
    const float* __restrict__ bih, const float* __restrict__ bhh)
{
    __shared__ __attribute__((aligned(16))) __half wlds[24576];
    __shared__ __attribute__((aligned(16))) __half aggh[64 * 72];
    __shared__ __attribute__((aligned(16))) __half xhs[64 * 72];
    const int tid = threadIdx.x;
    const int node0 = blockIdx.x * 64;

    {
        const uint4* src = (const uint4*)WG;
        uint4* dst = (uint4*)wlds;
        #pragma unroll
        for (int i = 0; i < 12; i++) dst[i * 256 + tid] = src[i * 256 + tid];
    }
    #pragma unroll
    for (int i = 0; i < 4; i++) {
        int idx4 = i * 256 + tid;
        int nl = idx4 >> 4, c4 = idx4 & 15;
        int node = node0 + nl;
        float4 a = make_float4(0.f, 0.f, 0.f, 0.f);
        if (node < NN) a = *(const float4*)(agg + (size_t)node * 64 + c4 * 4);
        __half2* ah = (__half2*)(aggh + nl * 72 + c4 * 4);
        ah[0] = __floats2half2_rn(a.x, a.y);
        ah[1] = __floats2half2_rn(a.z, a.w);
    }
    #pragma unroll
    for (int i = 0; i < 2; i++) {
        int idx8 = i * 256 + tid;
        int nl = idx8 >> 3, c8 = idx8 & 7;
        int node = node0 + nl;
        uint4 v = make_uint4(0, 0, 0, 0);
        if (node < NN) v = *(const uint4*)(xh + (size_t)node * 64 + c8 * 8);
        *(uint4*)(&xhs[nl * 72 + c8 * 8]) = v;
    }
    __syncthreads();

    const int w = tid >> 6, lane = tid & 63, m = lane & 15, quad = lane >> 4;
    const int nl_a = w * 16 + m;

    f16x8 a_agg[2], a_x[2];
    #pragma unroll
    for (int kt = 0; kt < 2; kt++) {
        const int koff = kt * 32 + quad * 8;
        a_agg[kt] = *(const f16x8*)(aggh + nl_a * 72 + koff);
        a_x[kt]   = *(const f16x8*)(xhs  + nl_a * 72 + koff);
    }

    f32x4 acc[24];
    #pragma unroll
    for (int nt = 0; nt < 24; nt++)
        #pragma unroll
        for (int q = 0; q < 4; q++) acc[nt][q] = 0.f;

    #pragma unroll
    for (int kt = 0; kt < 2; kt++) {
        #pragma unroll
        for (int nt = 0; nt < 24; nt++) {
            f16x8 b = *(const f16x8*)(wlds + (kt * 24 + nt) * 512 + m * 32 + quad * 8);
            acc[nt] = __builtin_amdgcn_mfma_f32_16x16x32_f16(
                (nt < 12) ? a_agg[kt] : a_x[kt], b, acc[nt], 0, 0, 0);
        }
    }

    #pragma unroll
    for (int t = 0; t < 4; t++) {
        const int h = t * 16 + m;
        const float bir = bih[h], biz = bih[64 + h], bin = bih[128 + h];
        const float bhr = bhh[h], bhz = bhh[64 + h], bhn = bhh[128 + h];
        #pragma unroll
        for (int r = 0; r < 4; r++) {
            const int nl = w * 16 + quad * 4 + r;
            float ir  = acc[t][r]      + bir;
            float iz  = acc[4 + t][r]  + biz;
            float in_ = acc[8 + t][r]  + bin;
            float hr  = acc[12 + t][r] + bhr;
            float hz  = acc[16 + t][r] + bhz;
            float hn  = acc[20 + t][r] + bhn;
            float rg = sigm(ir + hr);
            float z  = sigm(iz + hz);
            float n  = tanh_fast(in_ + rg * hn);
            float xold = __half2float(xhs[nl * 72 + h]);
            xhs[nl * 72 + h] = __float2half((1.0f - z) * n + z * xold);
        }
    }
    __syncthreads();

    #pragma unroll
    for (int i = 0; i < 2; i++) {
        int idx8 = i * 256 + tid;
        int nl = idx8 >> 3, c8 = idx8 & 7;
        int node = node0 + nl;
        if (node < NN)
            *(uint4*)(xh + (size_t)node * 64 + c8 * 8) = *(const uint4*)(&xhs[nl * 72 + c8 * 8]);
    }
    #pragma unroll
    for (int i = 0; i < 4; i++) {
        int idx4 = i * 256 + tid;
        int nl = idx4 >> 4, c4 = idx4 & 15;
        int node = node0 + nl;
        if (node < NN)
            *(float4*)(agg + (size_t)node * 64 + c4 * 4) = make_float4(0.f, 0.f, 0.f, 0.f);
    }
}

// Last GRU step fused with output projection + pooling.
__global__ __launch_bounds__(256, 2) void gru_pool_kernel(
    const float* __restrict__ agg, const __half* __restrict__ xh,
    const __half* __restrict__ WG,
    const float* __restrict__ bih, const float* __restrict__ bhh,
    const float* __restrict__ Wout, const float* __restrict__ bout,
    const int* __restrict__ batch, float* __restrict__ out)
{
    __shared__ __attribute__((aligned(16))) __half wlds[24576];
    __shared__ __attribute__((aligned(16))) __half aggh[64 * 72];
    __shared__ __attribute__((aligned(16))) __half xhs[64 * 72];
    const int tid = threadIdx.x;
    const int node0 = blockIdx.x * 64;

    {
        const uint4* src = (const uint4*)WG;
        uint4* dst = (uint4*)wlds;
        #pragma unroll
        for (int i = 0; i < 12; i++) dst[i * 256 + tid] = src[i * 256 + tid];
    }
    #pragma unroll
    for (int i = 0; i < 4; i++) {
        int idx4 = i * 256 + tid;
        int nl = idx4 >> 4, c4 = idx4 & 15;
        int node = node0 + nl;
        float4 a = make_float4(0.f, 0.f, 0.f, 0.f);
        if (node < NN) a = *(const float4*)(agg + (size_t)node * 64 + c4 * 4);
        __half2* ah = (__half2*)(aggh + nl * 72 + c4 * 4);
        ah[0] = __floats2half2_rn(a.x, a.y);
        ah[1] = __floats2half2_rn(a.z, a.w);
    }
    #pragma unroll
    for (int i = 0; i < 2; i++) {
        int idx8 = i * 256 + tid;
        int nl = idx8 >> 3, c8 = idx8 & 7;
        int node = node0 + nl;
        uint4 v = make_uint4(0, 0, 0, 0);
        if (node < NN) v = *(const uint4*)(xh + (size_t)node * 64 + c8 * 8);
        *(uint4*)(&xhs[nl * 72 + c8 * 8]) = v;
    }
    __syncthreads();

    const int w = tid >> 6, lane = tid & 63, m = lane & 15, quad = lane >> 4;
    const int nl_a = w * 16 + m;
    const int nbase = node0 + w * 16;

    f16x8 a_agg[2], a_x[2];
    #pragma unroll
    for (int kt = 0; kt < 2; kt++) {
        const int koff = kt * 32 + quad * 8;
        a_agg[kt] = *(const f16x8*)(aggh + nl_a * 72 + koff);
        a_x[kt]   = *(const f16x8*)(xhs  + nl_a * 72 + koff);
    }

    f32x4 acc[24];
    #pragma unroll
    for (int nt = 0; nt < 24; nt++)
        #pragma unroll
        for (int q = 0; q < 4; q++) acc[nt][q] = 0.f;

    #pragma unroll
    for (int kt = 0; kt < 2; kt++) {
        #pragma unroll
        for (int nt = 0; nt < 24; nt++) {
            f16x8 b = *(const f16x8*)(wlds + (kt * 24 + nt) * 512 + m * 32 + quad * 8);
            acc[nt] = __builtin_amdgcn_mfma_f32_16x16x32_f16(
                (nt < 12) ? a_agg[kt] : a_x[kt], b, acc[nt], 0, 0, 0);
        }
    }

    float po[4] = {0.f, 0.f, 0.f, 0.f};
    #pragma unroll
    for (int t = 0; t < 4; t++) {
        const int h = t * 16 + m;
        const float bir = bih[h], biz = bih[64 + h], bin = bih[128 + h];
        const float bhr = bhh[h], bhz = bhh[64 + h], bhn = bhh[128 + h];
        const float wo = Wout[h];
        #pragma unroll
        for (int r = 0; r < 4; r++) {
            const int nl = w * 16 + quad * 4 + r;
            float ir  = acc[t][r]      + bir;
            float iz  = acc[4 + t][r]  + biz;
            float in_ = acc[8 + t][r]  + bin;
            float hr  = acc[12 + t][r] + bhr;
            float hz  = acc[16 + t][r] + bhz;
            float hn  = acc[20 + t][r] + bhn;
            float rg = sigm(ir + hr);
            float z  = sigm(iz + hz);
            float n  = tanh_fast(in_ + rg * hn);
            float xold = __half2float(xhs[nl * 72 + h]);
            float xn = (1.0f - z) * n + z * xold;
            po[r] += xn * wo;
        }
    }
    #pragma unroll
    for (int off = 1; off < 16; off <<= 1) {
        #pragma unroll
        for (int r = 0; r < 4; r++) po[r] += __shfl_xor(po[r], off, 64);
    }
    if (m == 0) {
        const float b0 = bout[0];
        #pragma unroll
        for (int r = 0; r < 4; r++) {
            const int nd = nbase + quad * 4 + r;
            if (nd < NN) atomicAdd(out + batch[nd], po[r] + b0);
        }
    }
}

extern "C" void kernel_launch(void* const* d_in, const int* in_sizes, int n_in,
                              void* d_out, int out_size, void* d_ws, size_t ws_size,
                              hipStream_t stream)
{
    const float* nf   = (const float*)d_in[0];
    const float* ef   = (const float*)d_in[1];
    const int*   Esrc = (const int*)  d_in[2];
    const int*   Etgt = (const int*)  d_in[3];
    const int*   bat  = (const int*)  d_in[4];
    const float* Win  = (const float*)d_in[5];
    const float* bin_ = (const float*)d_in[6];
    const float* We1  = (const float*)d_in[7];
    const float* be1  = (const float*)d_in[8];
    const float* We2  = (const float*)d_in[9];
    const float* be2  = (const float*)d_in[10];
    const float* Wih  = (const float*)d_in[11];
    const float* bih  = (const float*)d_in[12];
    const float* Whh  = (const float*)d_in[13];
    const float* bhh  = (const float*)d_in[14];
    const float* Wout = (const float*)d_in[15];
    const float* bout = (const float*)d_in[16];

    char* ws = (char*)d_ws;
    float*  agg = (float*)(ws);                       // 12.8 MB
    __half* xh  = (__half*)(ws + 12800000);           // 6.4 MB
    __half* ehh = (__half*)(ws + 19200000);           // 12.8 MB
    __half* Bp  = (__half*)(ws + 32000000);           // 540,672 B (264 kt)
    __half* WG  = (__half*)(ws + 32600064);           // 49,152 B

    prologue_kernel<<<S5, 256, 0, stream>>>(
        nf, Win, bin_, ef, We1, be1, We2, be2, Wih, Whh,
        xh, ehh, Bp, WG, agg, (float*)d_out);

    const int msg_grid = (NE + 127) / 128;
    for (int t = 0; t < 2; t++) {
        msg_kernel<<<msg_grid, 128, 0, stream>>>(xh, ehh, Bp, Esrc, Etgt, agg);
        gru_kernel<<<(NN + 63) / 64, 256, 0, stream>>>(agg, xh, WG, bih, bhh);
    }
    msg_kernel<<<msg_grid, 128, 0, stream>>>(xh, ehh, Bp, Esrc, Etgt, agg);
    gru_pool_kernel<<<(NN + 63) / 64, 256, 0, stream>>>(
        agg, xh, WG, bih, bhh, Wout, bout, bat, (float*)d_out);
}